// Round 14
// baseline (905.960 us; speedup 1.0000x reference)
//
#include <hip/hip_runtime.h>
#include <stdint.h>

#define NA 50000
#define DD 256
#define NF 4
#define NG 50000
#define MM 150000
#define TOT 600000
#define NAP2 50048        // 391 * 128
#define NT2 391
#define KK 256            // K per GEMM (split concat)

typedef __attribute__((ext_vector_type(8))) short s16x8;
typedef __attribute__((ext_vector_type(4))) float f32x4;

__device__ __forceinline__ unsigned short f2bf(float f) {
  union { float f; uint32_t u; } v; v.f = f;
  return (unsigned short)((v.u + 0x7FFFu + ((v.u >> 16) & 1u)) >> 16);  // RNE
}
__device__ __forceinline__ float bf2f(unsigned short h) {
  union { uint32_t u; float f; } v; v.u = ((uint32_t)h) << 16; return v.f;
}
__device__ __forceinline__ void gld_lds16(const void* g, void* l) {
  __builtin_amdgcn_global_load_lds(
      (const __attribute__((address_space(1))) uint32_t*)g,
      (__attribute__((address_space(3))) uint32_t*)l, 16, 0, 0);
}

// f32 [b][50000][256] -> tiled bf16 [b][tile=grow/128][kb][c][row=grow%128][8]
__global__ void cvt_tile(const float* __restrict__ src, unsigned short* __restrict__ dst) {
  int blk = blockIdx.x;                 // ((b*391 + tile)*8 + kb)*2 + cp
  int cp = blk & 1, kb = (blk >> 1) & 7, rem = blk >> 4;
  int tile = rem % NT2, b = rem / NT2;
  int cl = threadIdx.x >> 7, row = threadIdx.x & 127;
  int c = cp * 2 + cl;
  int grow = tile * 128 + row;
  union { unsigned short h[8]; uint4 u; } o;
  if (grow < NA) {
    const float* s = src + ((size_t)b * NA + grow) * 256 + kb * 32 + c * 8;
    float4 v0 = *(const float4*)s, v1 = *(const float4*)(s + 4);
    o.h[0]=f2bf(v0.x); o.h[1]=f2bf(v0.y); o.h[2]=f2bf(v0.z); o.h[3]=f2bf(v0.w);
    o.h[4]=f2bf(v1.x); o.h[5]=f2bf(v1.y); o.h[6]=f2bf(v1.z); o.h[7]=f2bf(v1.w);
  } else o.u = make_uint4(0, 0, 0, 0);
  *(uint4*)(dst + (size_t)b * NAP2 * 256 +
            ((size_t)(tile * 8 + kb) * 512 + c * 128 + row) * 8) = o.u;
}

// Weight pre-chunk: slot = [kb][c][n], value[e]=W[kb*32+c*8+e][n].
//   slots [0,65536): top0 [f][nt]; [65536,131072): bot0; [131072,163840): top1 [f];
//   [163840,196608): bot1 [f]
__global__ void prep_w(const float* __restrict__ WM, const float* __restrict__ WU,
                       unsigned short* __restrict__ Wt) {
  int t = blockIdx.x * 256 + threadIdx.x;
  if (t >= 196608) return;
  const float* src;
  if (t < 131072) {
    int e = t & 65535;
    int f = e >> 14, nt = (e >> 13) & 1, r = e & 8191;
    int k = ((r >> 10) << 5) + (((r >> 8) & 3) << 3) + ((t >> 16) << 8);
    int n = r & 255;
    src = (nt ? WU : WM) + ((size_t)f * 512 + k) * 256 + n;
  } else {
    int e = t - 131072;
    int bot = e >> 15;
    e &= 32767;
    int f = e >> 13, r = e & 8191;
    int k = ((r >> 10) << 5) + (((r >> 8) & 3) << 3) + (bot << 8);
    int n = r & 255;
    src = WU + ((size_t)(NF + f) * 512 + k) * 256 + n;
  }
  union { unsigned short h[8]; uint4 u; } o;
#pragma unroll
  for (int e2 = 0; e2 < 8; ++e2) o.h[e2] = f2bf(src[(size_t)e2 * 256]);
  ((uint4*)Wt)[t] = o.u;
}

// ---- counting-sort CSR of flat_idx ----
__global__ void sort_count(const int* __restrict__ gi, uint32_t* __restrict__ cnt) {
  int t = blockIdx.x * 256 + threadIdx.x;
  if (t < TOT) atomicAdd(&cnt[gi[t]], 1u);
}
__global__ void sort_scan(const uint32_t* __restrict__ cnt, uint32_t* __restrict__ off,
                          uint32_t* __restrict__ bump) {
  __shared__ uint32_t part[1024];
  const int t = threadIdx.x;
  const int CH = 49;
  int lo = t * CH, hi = lo + CH; if (hi > NA) hi = NA;
  uint32_t s = 0;
  for (int i = lo; i < hi; ++i) s += cnt[i];
  part[t] = s;
  __syncthreads();
  for (int d = 1; d < 1024; d <<= 1) {
    uint32_t v = (t >= d) ? part[t - d] : 0u;
    __syncthreads();
    part[t] += v;
    __syncthreads();
  }
  uint32_t run = (t == 0) ? 0u : part[t - 1];
  for (int i = lo; i < hi; ++i) { off[i] = run; bump[i] = run; run += cnt[i]; }
  if (t == 1023) off[NA] = part[1023];
}
__global__ void sort_fill(const int* __restrict__ gi, uint32_t* __restrict__ bump,
                          uint32_t* __restrict__ occList) {
  int t = blockIdx.x * 256 + threadIdx.x;
  if (t < TOT) { uint32_t r = atomicAdd(&bump[gi[t]], 1u); occList[r] = (uint32_t)t; }
}

// Persistent-W GEMM — R7 schedule with ONE change: A-ring 3->4 buffers,
// prefetch depth 2->3 (issue load s+3 each step; steady wait vmcnt(2)).
// W (128KB) in LDS; ring 4x8KB -> 160KB total (HW max, proven in R9).
// Stores of tile t-1 at kb==0 of tile t, BEFORE the stage; unswapped MFMA.
template <int L>
__global__ __launch_bounds__(512, 2)
void pgemm(const unsigned short* __restrict__ Aatom,
           const unsigned short* __restrict__ Agcl,
           const unsigned short* __restrict__ Wt,
           unsigned short* __restrict__ Pa,
           unsigned short* __restrict__ Pg)
{
  constexpr int RW = (L == 0) ? 512 : 256;
  const int ch = blockIdx.x, w = blockIdx.y;
  int side, f, nt;
  if (L == 0) { side = w >> 3; f = (w >> 1) & 3; nt = w & 1; }
  else        { side = w >> 2; f = w & 3; nt = 0; }
  int tbase, tcnt;
  if (L == 0) { tbase = (ch < 7) ? ch * 25 : 175 + (ch - 7) * 24; tcnt = (ch < 7) ? 25 : 24; }
  else        { tbase = (ch < 7) ? ch * 13 : 91 + (ch - 7) * 12;  tcnt = (ch < 7) ? 13 : 12; }

  const size_t wslot = (L == 0) ? ((size_t)side * 65536 + (size_t)(f * 2 + nt) * 8192)
                                : ((size_t)131072 + (size_t)side * 32768 + (size_t)f * 8192);
  const unsigned short* Wm = Wt + wslot * 8;
  const unsigned short* Ab = side ? (Agcl + (size_t)f * NAP2 * 256) : Aatom;
  unsigned short* P = (side ? Pg : Pa) + (size_t)f * NAP2 * RW + nt * 256;

  const int tid = threadIdx.x, lane = tid & 63, wid = tid >> 6;
  const int wm = wid >> 2, wn = wid & 3;     // 2x4 wave grid: 64 rows x 64 cols each
  const int hi = lane >> 4, lo = lane & 15;

  __shared__ unsigned short Wl[65536];       // 128 KB
  __shared__ unsigned short Ar[4][4096];     // 4 x 8 KB ring (160 KB total)

  // stage W once
#pragma unroll
  for (int r = 0; r < 16; ++r)
    gld_lds16(Wm + ((size_t)(r * 8 + wid) * 64 + lane) * 8, &Wl[(r * 8 + wid) * 512]);

  const unsigned short* as = Ab + (size_t)tbase * 32768 + (size_t)(wid * 64 + lane) * 8;
  const int NS = tcnt * 8;

  f32x4 acc[4][4];
#pragma unroll
  for (int m = 0; m < 4; ++m)
#pragma unroll
    for (int n = 0; n < 4; ++n) acc[m][n] = (f32x4)0.f;

  // prologue: 3 A-steps in flight
  gld_lds16(as, &Ar[0][wid * 512]);
  gld_lds16(as + 4096, &Ar[1][wid * 512]);
  gld_lds16(as + 8192, &Ar[2][wid * 512]);

  for (int tl = 0; tl < tcnt; ++tl) {
#pragma unroll
    for (int kb = 0; kb < 8; ++kb) {
      const int s = tl * 8 + kb;
      if (s == NS - 1)      { asm volatile("s_waitcnt vmcnt(0)" ::: "memory"); }
      else if (s == NS - 2) { asm volatile("s_waitcnt vmcnt(1)" ::: "memory"); }
      else                  { asm volatile("s_waitcnt vmcnt(2)" ::: "memory"); }
      __builtin_amdgcn_sched_barrier(0);
      __builtin_amdgcn_s_barrier();
      __builtin_amdgcn_sched_barrier(0);

      if (kb == 0 && tl > 0) {
        // store previous tile (before staging)
        const size_t rb = (size_t)(tbase + tl - 1) * 128 + wm * 64;
#pragma unroll
        for (int m = 0; m < 4; ++m)
#pragma unroll
          for (int n = 0; n < 4; ++n) {
            int col = wn * 64 + n * 16 + lo;
#pragma unroll
            for (int r = 0; r < 4; ++r) {
              P[(rb + m * 16 + hi * 4 + r) * RW + col] = f2bf(acc[m][n][r]);
              acc[m][n][r] = 0.f;
            }
          }
      }
      if (s + 3 < NS)
        gld_lds16(as + (size_t)(s + 3) * 4096, &Ar[(s + 3) & 3][wid * 512]);

      const unsigned short* Abuf = Ar[s & 3];
      s16x8 bv[4], av[4];
#pragma unroll
      for (int n = 0; n < 4; ++n)
        bv[n] = *(const s16x8*)&Wl[(kb * 1024 + hi * 256 + wn * 64 + n * 16 + lo) * 8];
#pragma unroll
      for (int m = 0; m < 4; ++m)
        av[m] = *(const s16x8*)&Abuf[(hi * 128 + wm * 64 + m * 16 + lo) * 8];
#pragma unroll
      for (int m = 0; m < 4; ++m)
#pragma unroll
        for (int n = 0; n < 4; ++n)
          acc[m][n] = __builtin_amdgcn_mfma_f32_16x16x32_bf16(av[m], bv[n], acc[m][n], 0, 0, 0);
    }
  }
  // final tile store (vmcnt fully drained on last step)
  {
    const size_t rb = (size_t)(tbase + tcnt - 1) * 128 + wm * 64;
#pragma unroll
    for (int m = 0; m < 4; ++m)
#pragma unroll
      for (int n = 0; n < 4; ++n) {
        int col = wn * 64 + n * 16 + lo;
#pragma unroll
        for (int r = 0; r < 4; ++r)
          P[(rb + m * 16 + hi * 4 + r) * RW + col] = f2bf(acc[m][n][r]);
      }
  }
}

// L0 message combine: one 32-lane group per clique, uint4 (16B) gathers.
__global__ __launch_bounds__(256)
void msg_combine(const unsigned short* __restrict__ Pa,
                 const unsigned short* __restrict__ Pg,
                 const int* __restrict__ gIdx,
                 const float* __restrict__ bM,
                 unsigned short* __restrict__ gclT1)
{
  const int grp = blockIdx.x * 8 + (threadIdx.x >> 5);    // < NF*NAP2
  const int cl = threadIdx.x & 31;
  const int f = grp / NAP2, g = grp - f * NAP2;
  const int tile = g >> 7, row = g & 127;
  const int kb = cl >> 2, c = cl & 3;
  unsigned short* dp = gclT1 + (size_t)f * NAP2 * 256 +
                       ((size_t)(tile * 8 + kb) * 512 + c * 128 + row) * 8;
  if (g >= NG) { *(uint4*)dp = make_uint4(0, 0, 0, 0); return; }
  const int cc = cl * 8;
  const int* ip = gIdx + (size_t)f * MM + g * 3;
  int i0 = ip[0], i1 = ip[1], i2 = ip[2];
  const unsigned short* PaF = Pa + (size_t)f * NAP2 * 512;
  union { unsigned short h[8]; uint4 u; } a0, a1, a2, pg, o;
  a0.u = *(const uint4*)(PaF + (size_t)i0 * 512 + cc);
  a1.u = *(const uint4*)(PaF + (size_t)i1 * 512 + cc);
  a2.u = *(const uint4*)(PaF + (size_t)i2 * 512 + cc);
  pg.u = *(const uint4*)(Pg + ((size_t)f * NAP2 + g) * 512 + cc);
  const float4 b0 = *(const float4*)(bM + f * 256 + cc);
  const float4 b1 = *(const float4*)(bM + f * 256 + cc + 4);
  const float bb[8] = {b0.x, b0.y, b0.z, b0.w, b1.x, b1.y, b1.z, b1.w};
#pragma unroll
  for (int j = 0; j < 8; ++j) {
    float m = fmaxf(fmaxf(bf2f(a0.h[j]), bf2f(a1.h[j])), bf2f(a2.h[j]));
    o.h[j] = f2bf(fmaxf(m + bf2f(pg.h[j]) + bb[j], 0.f));
  }
  *(uint4*)dp = o.u;
}

// Update combine: out[a] = max(0, max_occ(Pa[f][a] + Pg[f][g] + bU[f])).
// One wave per atom; occurrence loop unrolled x4 (8/step across 2 half-waves)
// with independent Pg-row loads for memory-level parallelism.
template <int L>
__global__ __launch_bounds__(256)
void upd_combine(const unsigned short* __restrict__ Pa,
                 const unsigned short* __restrict__ Pg,
                 const uint32_t* __restrict__ offA,
                 const uint32_t* __restrict__ occList,
                 const float* __restrict__ bU,
                 unsigned short* __restrict__ outT,
                 float* __restrict__ outF)
{
  constexpr int RW = (L == 0) ? 512 : 256;
  constexpr int CO = (L == 0) ? 256 : 0;
  const int a = blockIdx.x * 4 + (threadIdx.x >> 6);
  const int lane = threadIdx.x & 63;
  const int h = lane >> 5, cl = lane & 31;
  const int cc = cl * 8;
  if (L == 0 && a >= NA) {
    if (a < NAP2 && h == 0) {
      int tile = a >> 7, row = a & 127;
      *(uint4*)(outT + ((size_t)(tile * 8 + (cl >> 2)) * 512 + (cl & 3) * 128 + row) * 8) =
          make_uint4(0, 0, 0, 0);
    }
    return;
  }
  if (a >= NA) return;

  float pa0[8], pa1[8], pa2[8], pa3[8];
  {
    union { unsigned short s[8]; uint4 u; } v;
#define LOADPA(F, DST)                                                          \
    v.u = *(const uint4*)(Pa + ((size_t)(F) * NAP2 + a) * RW + CO + cc);        \
    { const float4 b0 = *(const float4*)(bU + (F) * 256 + cc);                  \
      const float4 b1 = *(const float4*)(bU + (F) * 256 + cc + 4);              \
      DST[0]=bf2f(v.s[0])+b0.x; DST[1]=bf2f(v.s[1])+b0.y;                       \
      DST[2]=bf2f(v.s[2])+b0.z; DST[3]=bf2f(v.s[3])+b0.w;                       \
      DST[4]=bf2f(v.s[4])+b1.x; DST[5]=bf2f(v.s[5])+b1.y;                       \
      DST[6]=bf2f(v.s[6])+b1.z; DST[7]=bf2f(v.s[7])+b1.w; }
    LOADPA(0, pa0) LOADPA(1, pa1) LOADPA(2, pa2) LOADPA(3, pa3)
#undef LOADPA
  }

  float zm[8] = {0.f, 0.f, 0.f, 0.f, 0.f, 0.f, 0.f, 0.f};
  const uint32_t s = offA[a], e = offA[a + 1];
  for (uint32_t base = s; base < e; base += 64) {
    int cnt = (int)(e - base); if (cnt > 64) cnt = 64;
    uint32_t tmine = (base + lane < e) ? occList[base + lane] : 0u;
    int k = 0;
    // unrolled x4: 8 occurrences per iteration (4 per half-wave), independent loads
    for (; k + 8 <= cnt; k += 8) {
      uint32_t t0 = __shfl(tmine, k + h);
      uint32_t t1 = __shfl(tmine, k + 2 + h);
      uint32_t t2 = __shfl(tmine, k + 4 + h);
      uint32_t t3 = __shfl(tmine, k + 6 + h);
      int f0 = (int)(t0 / (uint32_t)MM), g0 = (int)((t0 - (uint32_t)f0 * MM) / 3u);
      int f1 = (int)(t1 / (uint32_t)MM), g1 = (int)((t1 - (uint32_t)f1 * MM) / 3u);
      int f2 = (int)(t2 / (uint32_t)MM), g2 = (int)((t2 - (uint32_t)f2 * MM) / 3u);
      int f3 = (int)(t3 / (uint32_t)MM), g3 = (int)((t3 - (uint32_t)f3 * MM) / 3u);
      union { unsigned short s[8]; uint4 u; } v0, v1, v2, v3;
      v0.u = *(const uint4*)(Pg + ((size_t)f0 * NAP2 + g0) * RW + CO + cc);
      v1.u = *(const uint4*)(Pg + ((size_t)f1 * NAP2 + g1) * RW + CO + cc);
      v2.u = *(const uint4*)(Pg + ((size_t)f2 * NAP2 + g2) * RW + CO + cc);
      v3.u = *(const uint4*)(Pg + ((size_t)f3 * NAP2 + g3) * RW + CO + cc);
#pragma unroll
      for (int j = 0; j < 8; ++j) {
        float p0 = (f0 == 0) ? pa0[j] : (f0 == 1) ? pa1[j] : (f0 == 2) ? pa2[j] : pa3[j];
        float p1 = (f1 == 0) ? pa0[j] : (f1 == 1) ? pa1[j] : (f1 == 2) ? pa2[j] : pa3[j];
        float p2 = (f2 == 0) ? pa0[j] : (f2 == 1) ? pa1[j] : (f2 == 2) ? pa2[j] : pa3[j];
        float p3 = (f3 == 0) ? pa0[j] : (f3 == 1) ? pa1[j] : (f3 == 2) ? pa2[j] : pa3[j];
        zm[j] = fmaxf(zm[j], fmaxf(fmaxf(p0 + bf2f(v0.s[j]), p1 + bf2f(v1.s[j])),
                                   fmaxf(p2 + bf2f(v2.s[j]), p3 + bf2f(v3.s[j]))));
      }
    }
    // remainder: 2 per step via half-waves
    for (; k < cnt; k += 2) {
      int src = k + h;
      uint32_t t = __shfl(tmine, src);
      if (src < cnt) {
        int f = (int)(t / (uint32_t)MM);
        int g = (int)((t - (uint32_t)f * MM) / 3u);
        union { unsigned short s[8]; uint4 u; } v;
        v.u = *(const uint4*)(Pg + ((size_t)f * NAP2 + g) * RW + CO + cc);
#pragma unroll
        for (int j = 0; j < 8; ++j) {
          float paf = (f == 0) ? pa0[j] : (f == 1) ? pa1[j] : (f == 2) ? pa2[j] : pa3[j];
          zm[j] = fmaxf(zm[j], paf + bf2f(v.s[j]));
        }
      }
    }
  }
  // merge half-waves
#pragma unroll
  for (int j = 0; j < 8; ++j) zm[j] = fmaxf(zm[j], __shfl_xor(zm[j], 32));

  if (L == 0) {
    if (h == 0) {
      union { unsigned short s[8]; uint4 u; } o;
#pragma unroll
      for (int j = 0; j < 8; ++j) o.s[j] = f2bf(zm[j]);
      int tile = a >> 7, row = a & 127;
      *(uint4*)(outT + ((size_t)(tile * 8 + (cl >> 2)) * 512 + (cl & 3) * 128 + row) * 8) = o.u;
    }
  } else {
    float4 o;
    if (h == 0) { o.x = zm[0]; o.y = zm[1]; o.z = zm[2]; o.w = zm[3];
                  *(float4*)(outF + (size_t)a * 256 + cc) = o; }
    else        { o.x = zm[4]; o.y = zm[5]; o.z = zm[6]; o.w = zm[7];
                  *(float4*)(outF + (size_t)a * 256 + cc + 4) = o; }
  }
}

extern "C" void kernel_launch(void* const* d_in, const int* in_sizes, int n_in,
                              void* d_out, int out_size, void* d_ws, size_t ws_size,
                              hipStream_t stream) {
  const float* x  = (const float*)d_in[0];
  const int*   gi = (const int*)d_in[1];
  const float* fg = (const float*)d_in[2];
  const float* WM = (const float*)d_in[3];
  const float* bM = (const float*)d_in[4];
  const float* WU = (const float*)d_in[5];
  const float* bU = (const float*)d_in[6];
  float* out = (float*)d_out;

  char* ws = (char*)d_ws;
  size_t off_b = 0;
  auto alloc = [&](size_t b) { char* p = ws + off_b; off_b += (b + 255) & ~(size_t)255; return p; };
  unsigned short* atomT = (unsigned short*)alloc((size_t)NAP2 * 256 * 2);      // 25.6 MB
  unsigned short* gclT  = (unsigned short*)alloc((size_t)NF * NAP2 * 256 * 2); // 102.5 MB
  unsigned short* P0a   = (unsigned short*)alloc((size_t)NF * NAP2 * 512 * 2); // 205 MB
  unsigned short* P0g   = (unsigned short*)alloc((size_t)NF * NAP2 * 512 * 2); // 205 MB
  unsigned short* Wt    = (unsigned short*)alloc((size_t)196608 * 16);         // 3.15 MB
  uint32_t* cnt     = (uint32_t*)alloc((size_t)NA * 4);
  uint32_t* offA    = (uint32_t*)alloc((size_t)(NA + 1) * 4);
  uint32_t* bump    = (uint32_t*)alloc((size_t)NA * 4);
  uint32_t* occList = (uint32_t*)alloc((size_t)TOT * 4);

  unsigned short* P1a = P0a;
  unsigned short* P1g = P0a + (size_t)NF * NAP2 * 256;

  cvt_tile<<<NT2 * 16, 256, 0, stream>>>(x, atomT);
  cvt_tile<<<NF * NT2 * 16, 256, 0, stream>>>(fg, gclT);
  prep_w<<<768, 256, 0, stream>>>(WM, WU, Wt);
  hipMemsetAsync(cnt, 0, (size_t)NA * 4, stream);
  sort_count<<<(TOT + 255) / 256, 256, 0, stream>>>(gi, cnt);
  sort_scan<<<1, 1024, 0, stream>>>(cnt, offA, bump);
  sort_fill<<<(TOT + 255) / 256, 256, 0, stream>>>(gi, bump, occList);

  // layer 0
  pgemm<0><<<dim3(16, 16), 512, 0, stream>>>(atomT, gclT, Wt, P0a, P0g);
  msg_combine<<<NF * NAP2 / 8, 256, 0, stream>>>(P0a, P0g, gi, bM, gclT);        // gclT := gcl1
  upd_combine<0><<<NAP2 / 4, 256, 0, stream>>>(P0a, P0g, offA, occList, bU, atomT, nullptr);

  // layer 1
  pgemm<1><<<dim3(32, 8), 512, 0, stream>>>(atomT, gclT, Wt, P1a, P1g);
  upd_combine<1><<<(NA + 3) / 4, 256, 0, stream>>>(P1a, P1g, offA, occList, bU + 1024, nullptr, out);
}

// Round 15
// 817.837 us; speedup vs baseline: 1.1078x; 1.1078x over previous
//
#include <hip/hip_runtime.h>
#include <stdint.h>

#define NA 50000
#define DD 256
#define NF 4
#define NG 50000
#define MM 150000
#define TOT 600000
#define NAP2 50048        // 391 * 128
#define NT2 391
#define KK 256            // K per GEMM (split concat)
#define MSGBLK (NF * NAP2 / 8)   // 25024
#define UPD0BLK (NAP2 / 4)       // 12512

typedef __attribute__((ext_vector_type(8))) short s16x8;
typedef __attribute__((ext_vector_type(4))) float f32x4;

__device__ __forceinline__ unsigned short f2bf(float f) {
  union { float f; uint32_t u; } v; v.f = f;
  return (unsigned short)((v.u + 0x7FFFu + ((v.u >> 16) & 1u)) >> 16);  // RNE
}
__device__ __forceinline__ float bf2f(unsigned short h) {
  union { uint32_t u; float f; } v; v.u = ((uint32_t)h) << 16; return v.f;
}
__device__ __forceinline__ void gld_lds16(const void* g, void* l) {
  __builtin_amdgcn_global_load_lds(
      (const __attribute__((address_space(1))) uint32_t*)g,
      (__attribute__((address_space(3))) uint32_t*)l, 16, 0, 0);
}

// Fused prep: cvt(x)->atomT | cvt(fg)->gclT | prep_w | sort_count, partitioned by blockIdx.
// cvt: f32 [b][50000][256] -> tiled bf16 [b][tile][kb][c][row][8]
// prep_w slots: [0,65536) top0 [f][nt]; [65536,131072) bot0; [131072,163840) top1; [163840,196608) bot1
__global__ __launch_bounds__(256)
void prep_all(const float* __restrict__ x, const float* __restrict__ fg,
              const float* __restrict__ WM, const float* __restrict__ WU,
              const int* __restrict__ gi,
              unsigned short* __restrict__ atomT, unsigned short* __restrict__ gclT,
              unsigned short* __restrict__ Wt, uint32_t* __restrict__ cnt)
{
  const int b = blockIdx.x, tid = threadIdx.x;
  if (b < 31280) {                                   // cvt: 6256 atom + 25024 gcl blocks
    const float* src; unsigned short* dst; int blk;
    if (b < 6256) { src = x; dst = atomT; blk = b; }
    else          { src = fg; dst = gclT; blk = b - 6256; }
    int cp = blk & 1, kb = (blk >> 1) & 7, rem = blk >> 4;
    int tile = rem % NT2, bb = rem / NT2;
    int cl = tid >> 7, row = tid & 127;
    int c = cp * 2 + cl;
    int grow = tile * 128 + row;
    union { unsigned short h[8]; uint4 u; } o;
    if (grow < NA) {
      const float* s = src + ((size_t)bb * NA + grow) * 256 + kb * 32 + c * 8;
      float4 v0 = *(const float4*)s, v1 = *(const float4*)(s + 4);
      o.h[0]=f2bf(v0.x); o.h[1]=f2bf(v0.y); o.h[2]=f2bf(v0.z); o.h[3]=f2bf(v0.w);
      o.h[4]=f2bf(v1.x); o.h[5]=f2bf(v1.y); o.h[6]=f2bf(v1.z); o.h[7]=f2bf(v1.w);
    } else o.u = make_uint4(0, 0, 0, 0);
    *(uint4*)(dst + (size_t)bb * NAP2 * 256 +
              ((size_t)(tile * 8 + kb) * 512 + c * 128 + row) * 8) = o.u;
  } else if (b < 32048) {                            // prep_w: 768 blocks
    int t = (b - 31280) * 256 + tid;
    if (t >= 196608) return;
    const float* src;
    if (t < 131072) {
      int e = t & 65535;
      int f = e >> 14, nt = (e >> 13) & 1, r = e & 8191;
      int k = ((r >> 10) << 5) + (((r >> 8) & 3) << 3) + ((t >> 16) << 8);
      int n = r & 255;
      src = (nt ? WU : WM) + ((size_t)f * 512 + k) * 256 + n;
    } else {
      int e = t - 131072;
      int bot = e >> 15;
      e &= 32767;
      int f = e >> 13, r = e & 8191;
      int k = ((r >> 10) << 5) + (((r >> 8) & 3) << 3) + (bot << 8);
      int n = r & 255;
      src = WU + ((size_t)(NF + f) * 512 + k) * 256 + n;
    }
    union { unsigned short h[8]; uint4 u; } o;
#pragma unroll
    for (int e2 = 0; e2 < 8; ++e2) o.h[e2] = f2bf(src[(size_t)e2 * 256]);
    ((uint4*)Wt)[t] = o.u;
  } else {                                           // sort_count: 2344 blocks
    int t = (b - 32048) * 256 + tid;
    if (t < TOT) atomicAdd(&cnt[gi[t]], 1u);
  }
}

__global__ void sort_scan(const uint32_t* __restrict__ cnt, uint32_t* __restrict__ off,
                          uint32_t* __restrict__ bump) {
  __shared__ uint32_t part[1024];
  const int t = threadIdx.x;
  const int CH = 49;
  int lo = t * CH, hi = lo + CH; if (hi > NA) hi = NA;
  uint32_t s = 0;
  for (int i = lo; i < hi; ++i) s += cnt[i];
  part[t] = s;
  __syncthreads();
  for (int d = 1; d < 1024; d <<= 1) {
    uint32_t v = (t >= d) ? part[t - d] : 0u;
    __syncthreads();
    part[t] += v;
    __syncthreads();
  }
  uint32_t run = (t == 0) ? 0u : part[t - 1];
  for (int i = lo; i < hi; ++i) { off[i] = run; bump[i] = run; run += cnt[i]; }
  if (t == 1023) off[NA] = part[1023];
}
__global__ void sort_fill(const int* __restrict__ gi, uint32_t* __restrict__ bump,
                          uint32_t* __restrict__ occList) {
  int t = blockIdx.x * 256 + threadIdx.x;
  if (t < TOT) { uint32_t r = atomicAdd(&bump[gi[t]], 1u); occList[r] = (uint32_t)t; }
}

// Persistent-W GEMM — the R7/R11/R13-benched ~197 µs kernel, VERBATIM.
// W (128KB) in LDS; A streamed through a 3x8KB ring, prefetch depth 2.
// Uniform vmcnt(1) waits (vmcnt(0) only at the last step); stores of tile t-1
// at kb==0 of tile t, BEFORE the stage; unswapped MFMA.
template <int L>
__global__ __launch_bounds__(512, 2)
void pgemm(const unsigned short* __restrict__ Aatom,
           const unsigned short* __restrict__ Agcl,
           const unsigned short* __restrict__ Wt,
           unsigned short* __restrict__ Pa,
           unsigned short* __restrict__ Pg)
{
  constexpr int RW = (L == 0) ? 512 : 256;
  const int ch = blockIdx.x, w = blockIdx.y;
  int side, f, nt;
  if (L == 0) { side = w >> 3; f = (w >> 1) & 3; nt = w & 1; }
  else        { side = w >> 2; f = w & 3; nt = 0; }
  int tbase, tcnt;
  if (L == 0) { tbase = (ch < 7) ? ch * 25 : 175 + (ch - 7) * 24; tcnt = (ch < 7) ? 25 : 24; }
  else        { tbase = (ch < 7) ? ch * 13 : 91 + (ch - 7) * 12;  tcnt = (ch < 7) ? 13 : 12; }

  const size_t wslot = (L == 0) ? ((size_t)side * 65536 + (size_t)(f * 2 + nt) * 8192)
                                : ((size_t)131072 + (size_t)side * 32768 + (size_t)f * 8192);
  const unsigned short* Wm = Wt + wslot * 8;
  const unsigned short* Ab = side ? (Agcl + (size_t)f * NAP2 * 256) : Aatom;
  unsigned short* P = (side ? Pg : Pa) + (size_t)f * NAP2 * RW + nt * 256;

  const int tid = threadIdx.x, lane = tid & 63, wid = tid >> 6;
  const int wm = wid >> 2, wn = wid & 3;     // 2x4 wave grid: 64 rows x 64 cols each
  const int hi = lane >> 4, lo = lane & 15;

  __shared__ unsigned short Wl[65536];       // 128 KB
  __shared__ unsigned short Ar[3][4096];     // 3 x 8 KB ring

  // stage W once
#pragma unroll
  for (int r = 0; r < 16; ++r)
    gld_lds16(Wm + ((size_t)(r * 8 + wid) * 64 + lane) * 8, &Wl[(r * 8 + wid) * 512]);

  const unsigned short* as = Ab + (size_t)tbase * 32768 + (size_t)(wid * 64 + lane) * 8;
  const int NS = tcnt * 8;

  f32x4 acc[4][4];
#pragma unroll
  for (int m = 0; m < 4; ++m)
#pragma unroll
    for (int n = 0; n < 4; ++n) acc[m][n] = (f32x4)0.f;

  // prologue: 2 A-steps in flight
  gld_lds16(as, &Ar[0][wid * 512]);
  gld_lds16(as + 4096, &Ar[1][wid * 512]);

  for (int tl = 0; tl < tcnt; ++tl) {
    const int bt = (tl * 2) % 3;             // ring phase of this tile's kb=0
#pragma unroll
    for (int kb = 0; kb < 8; ++kb) {
      const int s = tl * 8 + kb;
      if (s == NS - 1) { asm volatile("s_waitcnt vmcnt(0)" ::: "memory"); }
      else             { asm volatile("s_waitcnt vmcnt(1)" ::: "memory"); }
      __builtin_amdgcn_sched_barrier(0);
      __builtin_amdgcn_s_barrier();
      __builtin_amdgcn_sched_barrier(0);

      if (kb == 0 && tl > 0) {
        // store previous tile (before staging)
        const size_t rb = (size_t)(tbase + tl - 1) * 128 + wm * 64;
#pragma unroll
        for (int m = 0; m < 4; ++m)
#pragma unroll
          for (int n = 0; n < 4; ++n) {
            int col = wn * 64 + n * 16 + lo;
#pragma unroll
            for (int r = 0; r < 4; ++r) {
              P[(rb + m * 16 + hi * 4 + r) * RW + col] = f2bf(acc[m][n][r]);
              acc[m][n][r] = 0.f;
            }
          }
      }
      if (s + 2 < NS)
        gld_lds16(as + (size_t)(s + 2) * 4096, &Ar[(bt + ((kb + 2) % 3)) >= 3 ?
                  (bt + ((kb + 2) % 3)) - 3 : (bt + ((kb + 2) % 3))][wid * 512]);

      int buf = bt + (kb % 3); if (buf >= 3) buf -= 3;
      const unsigned short* Abuf = Ar[buf];
      s16x8 bv[4], av[4];
#pragma unroll
      for (int n = 0; n < 4; ++n)
        bv[n] = *(const s16x8*)&Wl[(kb * 1024 + hi * 256 + wn * 64 + n * 16 + lo) * 8];
#pragma unroll
      for (int m = 0; m < 4; ++m)
        av[m] = *(const s16x8*)&Abuf[(hi * 128 + wm * 64 + m * 16 + lo) * 8];
#pragma unroll
      for (int m = 0; m < 4; ++m)
#pragma unroll
        for (int n = 0; n < 4; ++n)
          acc[m][n] = __builtin_amdgcn_mfma_f32_16x16x32_bf16(av[m], bv[n], acc[m][n], 0, 0, 0);
    }
  }
  // final tile store (vmcnt fully drained on last step)
  {
    const size_t rb = (size_t)(tbase + tcnt - 1) * 128 + wm * 64;
#pragma unroll
    for (int m = 0; m < 4; ++m)
#pragma unroll
      for (int n = 0; n < 4; ++n) {
        int col = wn * 64 + n * 16 + lo;
#pragma unroll
        for (int r = 0; r < 4; ++r)
          P[(rb + m * 16 + hi * 4 + r) * RW + col] = f2bf(acc[m][n][r]);
      }
  }
}

// Fused post-L0 combine: msg (blocks [0,MSGBLK)) + upd L=0 (blocks [MSGBLK, MSGBLK+UPD0BLK)).
// Bodies are verbatim from R13's msg_combine / upd_combine<0>.
__global__ __launch_bounds__(256)
void combine0(const unsigned short* __restrict__ Pa,
              const unsigned short* __restrict__ Pg,
              const int* __restrict__ gIdx,
              const float* __restrict__ bM,
              const float* __restrict__ bU,
              const uint32_t* __restrict__ offA,
              const uint32_t* __restrict__ occList,
              unsigned short* __restrict__ gclT1,
              unsigned short* __restrict__ atomT1)
{
  if (blockIdx.x < MSGBLK) {
    // ---- msg: one 32-lane group per clique ----
    const int grp = blockIdx.x * 8 + (threadIdx.x >> 5);
    const int cl = threadIdx.x & 31;
    const int f = grp / NAP2, g = grp - f * NAP2;
    const int tile = g >> 7, row = g & 127;
    const int kb = cl >> 2, c = cl & 3;
    unsigned short* dp = gclT1 + (size_t)f * NAP2 * 256 +
                         ((size_t)(tile * 8 + kb) * 512 + c * 128 + row) * 8;
    if (g >= NG) { *(uint4*)dp = make_uint4(0, 0, 0, 0); return; }
    const int cc = cl * 8;
    const int* ip = gIdx + (size_t)f * MM + g * 3;
    int i0 = ip[0], i1 = ip[1], i2 = ip[2];
    const unsigned short* PaF = Pa + (size_t)f * NAP2 * 512;
    union { unsigned short h[8]; uint4 u; } a0, a1, a2, pg, o;
    a0.u = *(const uint4*)(PaF + (size_t)i0 * 512 + cc);
    a1.u = *(const uint4*)(PaF + (size_t)i1 * 512 + cc);
    a2.u = *(const uint4*)(PaF + (size_t)i2 * 512 + cc);
    pg.u = *(const uint4*)(Pg + ((size_t)f * NAP2 + g) * 512 + cc);
    const float4 b0 = *(const float4*)(bM + f * 256 + cc);
    const float4 b1 = *(const float4*)(bM + f * 256 + cc + 4);
    const float bb[8] = {b0.x, b0.y, b0.z, b0.w, b1.x, b1.y, b1.z, b1.w};
#pragma unroll
    for (int j = 0; j < 8; ++j) {
      float m = fmaxf(fmaxf(bf2f(a0.h[j]), bf2f(a1.h[j])), bf2f(a2.h[j]));
      o.h[j] = f2bf(fmaxf(m + bf2f(pg.h[j]) + bb[j], 0.f));
    }
    *(uint4*)dp = o.u;
  } else {
    // ---- upd L=0: one wave per atom, x4-unrolled occurrence walk ----
    const int a = (int)(blockIdx.x - MSGBLK) * 4 + (threadIdx.x >> 6);
    const int lane = threadIdx.x & 63;
    const int h = lane >> 5, cl = lane & 31;
    const int cc = cl * 8;
    if (a >= NA) {
      if (a < NAP2 && h == 0) {
        int tile = a >> 7, row = a & 127;
        *(uint4*)(atomT1 + ((size_t)(tile * 8 + (cl >> 2)) * 512 + (cl & 3) * 128 + row) * 8) =
            make_uint4(0, 0, 0, 0);
      }
      return;
    }

    float pa0[8], pa1[8], pa2[8], pa3[8];
    {
      union { unsigned short s[8]; uint4 u; } v;
#define LOADPA(F, DST)                                                          \
      v.u = *(const uint4*)(Pa + ((size_t)(F) * NAP2 + a) * 512 + 256 + cc);    \
      { const float4 b0 = *(const float4*)(bU + (F) * 256 + cc);                \
        const float4 b1 = *(const float4*)(bU + (F) * 256 + cc + 4);            \
        DST[0]=bf2f(v.s[0])+b0.x; DST[1]=bf2f(v.s[1])+b0.y;                     \
        DST[2]=bf2f(v.s[2])+b0.z; DST[3]=bf2f(v.s[3])+b0.w;                     \
        DST[4]=bf2f(v.s[4])+b1.x; DST[5]=bf2f(v.s[5])+b1.y;                     \
        DST[6]=bf2f(v.s[6])+b1.z; DST[7]=bf2f(v.s[7])+b1.w; }
      LOADPA(0, pa0) LOADPA(1, pa1) LOADPA(2, pa2) LOADPA(3, pa3)
#undef LOADPA
    }

    float zm[8] = {0.f, 0.f, 0.f, 0.f, 0.f, 0.f, 0.f, 0.f};
    const uint32_t s = offA[a], e = offA[a + 1];
    for (uint32_t base = s; base < e; base += 64) {
      int cnt = (int)(e - base); if (cnt > 64) cnt = 64;
      uint32_t tmine = (base + lane < e) ? occList[base + lane] : 0u;
      int k = 0;
      for (; k + 8 <= cnt; k += 8) {
        uint32_t t0 = __shfl(tmine, k + h);
        uint32_t t1 = __shfl(tmine, k + 2 + h);
        uint32_t t2 = __shfl(tmine, k + 4 + h);
        uint32_t t3 = __shfl(tmine, k + 6 + h);
        int f0 = (int)(t0 / (uint32_t)MM), g0 = (int)((t0 - (uint32_t)f0 * MM) / 3u);
        int f1 = (int)(t1 / (uint32_t)MM), g1 = (int)((t1 - (uint32_t)f1 * MM) / 3u);
        int f2 = (int)(t2 / (uint32_t)MM), g2 = (int)((t2 - (uint32_t)f2 * MM) / 3u);
        int f3 = (int)(t3 / (uint32_t)MM), g3 = (int)((t3 - (uint32_t)f3 * MM) / 3u);
        union { unsigned short s[8]; uint4 u; } v0, v1, v2, v3;
        v0.u = *(const uint4*)(Pg + ((size_t)f0 * NAP2 + g0) * 512 + 256 + cc);
        v1.u = *(const uint4*)(Pg + ((size_t)f1 * NAP2 + g1) * 512 + 256 + cc);
        v2.u = *(const uint4*)(Pg + ((size_t)f2 * NAP2 + g2) * 512 + 256 + cc);
        v3.u = *(const uint4*)(Pg + ((size_t)f3 * NAP2 + g3) * 512 + 256 + cc);
#pragma unroll
        for (int j = 0; j < 8; ++j) {
          float p0 = (f0 == 0) ? pa0[j] : (f0 == 1) ? pa1[j] : (f0 == 2) ? pa2[j] : pa3[j];
          float p1 = (f1 == 0) ? pa0[j] : (f1 == 1) ? pa1[j] : (f1 == 2) ? pa2[j] : pa3[j];
          float p2 = (f2 == 0) ? pa0[j] : (f2 == 1) ? pa1[j] : (f2 == 2) ? pa2[j] : pa3[j];
          float p3 = (f3 == 0) ? pa0[j] : (f3 == 1) ? pa1[j] : (f3 == 2) ? pa2[j] : pa3[j];
          zm[j] = fmaxf(zm[j], fmaxf(fmaxf(p0 + bf2f(v0.s[j]), p1 + bf2f(v1.s[j])),
                                     fmaxf(p2 + bf2f(v2.s[j]), p3 + bf2f(v3.s[j]))));
        }
      }
      for (; k < cnt; k += 2) {
        int src = k + h;
        uint32_t t = __shfl(tmine, src);
        if (src < cnt) {
          int f = (int)(t / (uint32_t)MM);
          int g = (int)((t - (uint32_t)f * MM) / 3u);
          union { unsigned short s[8]; uint4 u; } v;
          v.u = *(const uint4*)(Pg + ((size_t)f * NAP2 + g) * 512 + 256 + cc);
#pragma unroll
          for (int j = 0; j < 8; ++j) {
            float paf = (f == 0) ? pa0[j] : (f == 1) ? pa1[j] : (f == 2) ? pa2[j] : pa3[j];
            zm[j] = fmaxf(zm[j], paf + bf2f(v.s[j]));
          }
        }
      }
    }
#pragma unroll
    for (int j = 0; j < 8; ++j) zm[j] = fmaxf(zm[j], __shfl_xor(zm[j], 32));

    if (h == 0) {
      union { unsigned short s[8]; uint4 u; } o;
#pragma unroll
      for (int j = 0; j < 8; ++j) o.s[j] = f2bf(zm[j]);
      int tile = a >> 7, row = a & 127;
      *(uint4*)(atomT1 + ((size_t)(tile * 8 + (cl >> 2)) * 512 + (cl & 3) * 128 + row) * 8) = o.u;
    }
  }
}

// Update combine L=1 (final output, f32): verbatim R13.
__global__ __launch_bounds__(256)
void upd_combine1(const unsigned short* __restrict__ Pa,
                  const unsigned short* __restrict__ Pg,
                  const uint32_t* __restrict__ offA,
                  const uint32_t* __restrict__ occList,
                  const float* __restrict__ bU,
                  float* __restrict__ outF)
{
  const int a = blockIdx.x * 4 + (threadIdx.x >> 6);
  const int lane = threadIdx.x & 63;
  const int h = lane >> 5, cl = lane & 31;
  const int cc = cl * 8;
  if (a >= NA) return;

  float pa0[8], pa1[8], pa2[8], pa3[8];
  {
    union { unsigned short s[8]; uint4 u; } v;
#define LOADPA(F, DST)                                                          \
    v.u = *(const uint4*)(Pa + ((size_t)(F) * NAP2 + a) * 256 + cc);            \
    { const float4 b0 = *(const float4*)(bU + (F) * 256 + cc);                  \
      const float4 b1 = *(const float4*)(bU + (F) * 256 + cc + 4);              \
      DST[0]=bf2f(v.s[0])+b0.x; DST[1]=bf2f(v.s[1])+b0.y;                       \
      DST[2]=bf2f(v.s[2])+b0.z; DST[3]=bf2f(v.s[3])+b0.w;                       \
      DST[4]=bf2f(v.s[4])+b1.x; DST[5]=bf2f(v.s[5])+b1.y;                       \
      DST[6]=bf2f(v.s[6])+b1.z; DST[7]=bf2f(v.s[7])+b1.w; }
    LOADPA(0, pa0) LOADPA(1, pa1) LOADPA(2, pa2) LOADPA(3, pa3)
#undef LOADPA
  }

  float zm[8] = {0.f, 0.f, 0.f, 0.f, 0.f, 0.f, 0.f, 0.f};
  const uint32_t s = offA[a], e = offA[a + 1];
  for (uint32_t base = s; base < e; base += 64) {
    int cnt = (int)(e - base); if (cnt > 64) cnt = 64;
    uint32_t tmine = (base + lane < e) ? occList[base + lane] : 0u;
    int k = 0;
    for (; k + 8 <= cnt; k += 8) {
      uint32_t t0 = __shfl(tmine, k + h);
      uint32_t t1 = __shfl(tmine, k + 2 + h);
      uint32_t t2 = __shfl(tmine, k + 4 + h);
      uint32_t t3 = __shfl(tmine, k + 6 + h);
      int f0 = (int)(t0 / (uint32_t)MM), g0 = (int)((t0 - (uint32_t)f0 * MM) / 3u);
      int f1 = (int)(t1 / (uint32_t)MM), g1 = (int)((t1 - (uint32_t)f1 * MM) / 3u);
      int f2 = (int)(t2 / (uint32_t)MM), g2 = (int)((t2 - (uint32_t)f2 * MM) / 3u);
      int f3 = (int)(t3 / (uint32_t)MM), g3 = (int)((t3 - (uint32_t)f3 * MM) / 3u);
      union { unsigned short s[8]; uint4 u; } v0, v1, v2, v3;
      v0.u = *(const uint4*)(Pg + ((size_t)f0 * NAP2 + g0) * 256 + cc);
      v1.u = *(const uint4*)(Pg + ((size_t)f1 * NAP2 + g1) * 256 + cc);
      v2.u = *(const uint4*)(Pg + ((size_t)f2 * NAP2 + g2) * 256 + cc);
      v3.u = *(const uint4*)(Pg + ((size_t)f3 * NAP2 + g3) * 256 + cc);
#pragma unroll
      for (int j = 0; j < 8; ++j) {
        float p0 = (f0 == 0) ? pa0[j] : (f0 == 1) ? pa1[j] : (f0 == 2) ? pa2[j] : pa3[j];
        float p1 = (f1 == 0) ? pa0[j] : (f1 == 1) ? pa1[j] : (f1 == 2) ? pa2[j] : pa3[j];
        float p2 = (f2 == 0) ? pa0[j] : (f2 == 1) ? pa1[j] : (f2 == 2) ? pa2[j] : pa3[j];
        float p3 = (f3 == 0) ? pa0[j] : (f3 == 1) ? pa1[j] : (f3 == 2) ? pa2[j] : pa3[j];
        zm[j] = fmaxf(zm[j], fmaxf(fmaxf(p0 + bf2f(v0.s[j]), p1 + bf2f(v1.s[j])),
                                   fmaxf(p2 + bf2f(v2.s[j]), p3 + bf2f(v3.s[j]))));
      }
    }
    for (; k < cnt; k += 2) {
      int src = k + h;
      uint32_t t = __shfl(tmine, src);
      if (src < cnt) {
        int f = (int)(t / (uint32_t)MM);
        int g = (int)((t - (uint32_t)f * MM) / 3u);
        union { unsigned short s[8]; uint4 u; } v;
        v.u = *(const uint4*)(Pg + ((size_t)f * NAP2 + g) * 256 + cc);
#pragma unroll
        for (int j = 0; j < 8; ++j) {
          float paf = (f == 0) ? pa0[j] : (f == 1) ? pa1[j] : (f == 2) ? pa2[j] : pa3[j];
          zm[j] = fmaxf(zm[j], paf + bf2f(v.s[j]));
        }
      }
    }
  }
#pragma unroll
  for (int j = 0; j < 8; ++j) zm[j] = fmaxf(zm[j], __shfl_xor(zm[j], 32));

  float4 o;
  if (h == 0) { o.x = zm[0]; o.y = zm[1]; o.z = zm[2]; o.w = zm[3];
                *(float4*)(outF + (size_t)a * 256 + cc) = o; }
  else        { o.x = zm[4]; o.y = zm[5]; o.z = zm[6]; o.w = zm[7];
                *(float4*)(outF + (size_t)a * 256 + cc + 4) = o; }
}

extern "C" void kernel_launch(void* const* d_in, const int* in_sizes, int n_in,
                              void* d_out, int out_size, void* d_ws, size_t ws_size,
                              hipStream_t stream) {
  const float* x  = (const float*)d_in[0];
  const int*   gi = (const int*)d_in[1];
  const float* fg = (const float*)d_in[2];
  const float* WM = (const float*)d_in[3];
  const float* bM = (const float*)d_in[4];
  const float* WU = (const float*)d_in[5];
  const float* bU = (const float*)d_in[6];
  float* out = (float*)d_out;

  char* ws = (char*)d_ws;
  size_t off_b = 0;
  auto alloc = [&](size_t b) { char* p = ws + off_b; off_b += (b + 255) & ~(size_t)255; return p; };
  unsigned short* atomT = (unsigned short*)alloc((size_t)NAP2 * 256 * 2);      // 25.6 MB
  unsigned short* gclT  = (unsigned short*)alloc((size_t)NF * NAP2 * 256 * 2); // 102.5 MB
  unsigned short* P0a   = (unsigned short*)alloc((size_t)NF * NAP2 * 512 * 2); // 205 MB
  unsigned short* P0g   = (unsigned short*)alloc((size_t)NF * NAP2 * 512 * 2); // 205 MB
  unsigned short* Wt    = (unsigned short*)alloc((size_t)196608 * 16);         // 3.15 MB
  uint32_t* cnt     = (uint32_t*)alloc((size_t)NA * 4);
  uint32_t* offA    = (uint32_t*)alloc((size_t)(NA + 1) * 4);
  uint32_t* bump    = (uint32_t*)alloc((size_t)NA * 4);
  uint32_t* occList = (uint32_t*)alloc((size_t)TOT * 4);

  unsigned short* P1a = P0a;
  unsigned short* P1g = P0a + (size_t)NF * NAP2 * 256;

  hipMemsetAsync(cnt, 0, (size_t)NA * 4, stream);
  prep_all<<<34392, 256, 0, stream>>>(x, fg, WM, WU, gi, atomT, gclT, Wt, cnt);
  sort_scan<<<1, 1024, 0, stream>>>(cnt, offA, bump);
  sort_fill<<<(TOT + 255) / 256, 256, 0, stream>>>(gi, bump, occList);

  // layer 0
  pgemm<0><<<dim3(16, 16), 512, 0, stream>>>(atomT, gclT, Wt, P0a, P0g);
  combine0<<<MSGBLK + UPD0BLK, 256, 0, stream>>>(P0a, P0g, gi, bM, bU, offA, occList,
                                                 gclT, atomT);   // gclT := gcl1, atomT := atom1

  // layer 1
  pgemm<1><<<dim3(32, 8), 512, 0, stream>>>(atomT, gclT, Wt, P1a, P1g);
  upd_combine1<<<(NA + 3) / 4, 256, 0, stream>>>(P1a, P1g, offA, occList, bU + 1024, out);
}